// Round 10
// baseline (357.994 us; speedup 1.0000x reference)
//
#include <hip/hip_runtime.h>
#include <hip/hip_bf16.h>

#define C_ 256
#define N_ 4096
#define CN (C_*N_)
#define EPSF 1e-5f
#define NS_ITERS 6
#define KSPLIT 32  // split-K for MFMA cov partials (512 blocks = 2/CU)
#define LSTR 40   // LDS row stride in ushort (80 B, 16B-aligned)

typedef _Float16 f16x8 __attribute__((ext_vector_type(8)));
typedef float f32x4 __attribute__((ext_vector_type(4)));

__device__ __forceinline__ int refl(int t) {
  return t < 0 ? -t : (t > 63 ? 126 - t : t);
}

// fp16 2-way split: v = h + l exact to ~2^-22 rel.
__device__ __forceinline__ unsigned short f2h(float x) {
  _Float16 h = (_Float16)x;
  return __builtin_bit_cast(unsigned short, h);
}
__device__ __forceinline__ float h2f(unsigned short u) {
  return (float)__builtin_bit_cast(_Float16, u);
}

// ---------------- shared MFMA helper: 64x64 out tile of A·B^T, K=256, fp32 in ----------------
__device__ __forceinline__ void mm64_3term(unsigned short* sm, const float* A, const float* B,
                                           int m0, int n0, f32x4 acc[2][2]) {
  const int P = 64*LSTR;
  int t = threadIdx.x;
  int lane = t & 63;
  int wv = (t >> 7) & 1, wu = (t >> 6) & 1;
  int lx16 = lane & 15, quad = lane >> 4;
  int srow = t >> 2, sseg = (t & 3) * 8;
#pragma unroll
  for (int i = 0; i < 2; i++)
#pragma unroll
    for (int j = 0; j < 2; j++) acc[i][j] = (f32x4){0.f, 0.f, 0.f, 0.f};
  for (int k0 = 0; k0 < 256; k0 += 32) {
    __syncthreads();
    {
      const float* pa = &A[(size_t)(m0 + srow)*256 + k0 + sseg];
      const float* pb = &B[(size_t)(n0 + srow)*256 + k0 + sseg];
#pragma unroll
      for (int g = 0; g < 2; g++) {
        float4 va = *(const float4*)(pa + g*4);
        float4 vb = *(const float4*)(pb + g*4);
        float fa[4] = {va.x, va.y, va.z, va.w};
        float fb[4] = {vb.x, vb.y, vb.z, vb.w};
        unsigned short ha[4], la[4], hb[4], lb[4];
#pragma unroll
        for (int j = 0; j < 4; j++) {
          unsigned short h = f2h(fa[j]); ha[j] = h; la[j] = f2h(fa[j] - h2f(h));
          h = f2h(fb[j]); hb[j] = h; lb[j] = f2h(fb[j] - h2f(h));
        }
        int lo_ = srow*LSTR + sseg + g*4;
        *(ushort4*)&sm[0*P + lo_] = make_ushort4(ha[0], ha[1], ha[2], ha[3]);
        *(ushort4*)&sm[1*P + lo_] = make_ushort4(la[0], la[1], la[2], la[3]);
        *(ushort4*)&sm[2*P + lo_] = make_ushort4(hb[0], hb[1], hb[2], hb[3]);
        *(ushort4*)&sm[3*P + lo_] = make_ushort4(lb[0], lb[1], lb[2], lb[3]);
      }
    }
    __syncthreads();
    f16x8 ah[2], al[2], bh[2], bl[2];
#pragma unroll
    for (int mt = 0; mt < 2; mt++) {
      int arow = (wv*32 + mt*16 + lx16)*LSTR + quad*8;
      ah[mt] = *(const f16x8*)&sm[0*P + arow];
      al[mt] = *(const f16x8*)&sm[1*P + arow];
    }
#pragma unroll
    for (int nt = 0; nt < 2; nt++) {
      int brow = (wu*32 + nt*16 + lx16)*LSTR + quad*8;
      bh[nt] = *(const f16x8*)&sm[2*P + brow];
      bl[nt] = *(const f16x8*)&sm[3*P + brow];
    }
#pragma unroll
    for (int mt = 0; mt < 2; mt++)
#pragma unroll
      for (int nt = 0; nt < 2; nt++) {
        f32x4 a = acc[mt][nt];
        a = __builtin_amdgcn_mfma_f32_16x16x32_f16(ah[mt], bh[nt], a, 0, 0, 0);
        a = __builtin_amdgcn_mfma_f32_16x16x32_f16(ah[mt], bl[nt], a, 0, 0, 0);
        a = __builtin_amdgcn_mfma_f32_16x16x32_f16(al[mt], bh[nt], a, 0, 0, 0);
        acc[mt][nt] = a;
      }
  }
}

// ---------------- mm32: 32x32 out tile of A·B^T, K=256, fp32 in (NS parallelism) ----------
__device__ __forceinline__ f32x4 mm32_3term(unsigned short* sm, const float* A, const float* B,
                                            int m0, int n0) {
  const int P = 32*LSTR;
  int t = threadIdx.x, lane = t & 63;
  int w = t >> 6, wv = w >> 1, wu = w & 1;
  int lx16 = lane & 15, quad = lane >> 4;
  int mat = t >> 7, srow = (t >> 2) & 31, sseg = (t & 3) * 8;
  const float* S = mat ? B : A;
  int rb = mat ? n0 : m0;
  int base0 = mat ? 2*P : 0;
  f32x4 acc = (f32x4){0.f, 0.f, 0.f, 0.f};
  for (int k0 = 0; k0 < 256; k0 += 32) {
    __syncthreads();
    {
      const float* p = &S[(size_t)(rb + srow)*256 + k0 + sseg];
      int lo_ = srow*LSTR + sseg;
#pragma unroll
      for (int g = 0; g < 2; g++) {
        float4 v = *(const float4*)(p + g*4);
        float f[4] = {v.x, v.y, v.z, v.w};
        unsigned short hh[4], ll[4];
#pragma unroll
        for (int j = 0; j < 4; j++) {
          unsigned short h = f2h(f[j]); hh[j] = h; ll[j] = f2h(f[j] - h2f(h));
        }
        *(ushort4*)&sm[base0 + lo_ + g*4]     = make_ushort4(hh[0], hh[1], hh[2], hh[3]);
        *(ushort4*)&sm[base0 + P + lo_ + g*4] = make_ushort4(ll[0], ll[1], ll[2], ll[3]);
      }
    }
    __syncthreads();
    int arow = (wv*16 + lx16)*LSTR + quad*8;
    int brow = (wu*16 + lx16)*LSTR + quad*8;
    f16x8 ah = *(const f16x8*)&sm[0*P + arow];
    f16x8 al = *(const f16x8*)&sm[1*P + arow];
    f16x8 bh = *(const f16x8*)&sm[2*P + brow];
    f16x8 bl = *(const f16x8*)&sm[3*P + brow];
    acc = __builtin_amdgcn_mfma_f32_16x16x32_f16(ah, bh, acc, 0, 0, 0);
    acc = __builtin_amdgcn_mfma_f32_16x16x32_f16(ah, bl, acc, 0, 0, 0);
    acc = __builtin_amdgcn_mfma_f32_16x16x32_f16(al, bh, acc, 0, 0, 0);
  }
  return acc;
}

// ---------------- means (float4-vectorized) ----------------
__global__ __launch_bounds__(256) void k_mean(const float* content, const float* style,
                                              float* means) {
  int c = blockIdx.x, m = blockIdx.y, t = threadIdx.x;
  const float* x = (m < 2 ? content : style) + (size_t)(m & 1) * CN + (size_t)c * N_;
  const float4* x4 = (const float4*)x;
  float s = 0.f;
#pragma unroll
  for (int i = 0; i < 4; i++) {
    float4 v = x4[t + i*256];
    s += v.x + v.y + v.z + v.w;
  }
  __shared__ float red[256];
  red[t] = s; __syncthreads();
  for (int off = 128; off > 0; off >>= 1) { if (t < off) red[t] += red[t + off]; __syncthreads(); }
  if (t == 0) means[m * C_ + c] = red[0] * (1.f / N_);
}

// ---------------- fused split: raw [c][n] planes for cov + mean-sub transposed [v][c] planes ----
__global__ __launch_bounds__(256) void k_splitall(const float* content, const float* style,
                                                  const float* means,
                                                  unsigned short* covsp, unsigned short* xcT) {
  int m = blockIdx.z;
  const float* x = (m < 2 ? content : style) + (size_t)(m & 1) * CN;
  int u0 = blockIdx.x * 32, c0 = blockIdx.y * 32;
  unsigned short* ch_ = covsp + (size_t)(2*m+0)*CN;
  unsigned short* cl_ = covsp + (size_t)(2*m+1)*CN;
  unsigned short* th_ = xcT + (size_t)(2*m+0)*CN;
  unsigned short* tl_ = xcT + (size_t)(2*m+1)*CN;
  __shared__ float tile[32][33];
  int t = threadIdx.x;
  {
    int cc = t >> 3, uu4 = (t & 7) * 4;
    float4 v = *(const float4*)&x[(size_t)(c0+cc)*N_ + u0 + uu4];
    float f[4] = {v.x, v.y, v.z, v.w};
    unsigned short h[4], lo[4];
#pragma unroll
    for (int j = 0; j < 4; j++) {
      unsigned short hh = f2h(f[j]);
      h[j] = hh; lo[j] = f2h(f[j] - h2f(hh));
      tile[cc][uu4+j] = f[j];
    }
    size_t o = (size_t)(c0+cc)*N_ + u0 + uu4;
    *(ushort4*)&ch_[o] = make_ushort4(h[0], h[1], h[2], h[3]);
    *(ushort4*)&cl_[o] = make_ushort4(lo[0], lo[1], lo[2], lo[3]);
  }
  __syncthreads();
  {
    int uu = t >> 3, cc4 = (t & 7) * 4;
    unsigned short h[4], lo[4];
#pragma unroll
    for (int j = 0; j < 4; j++) {
      float v = tile[cc4+j][uu] - means[m*C_ + c0 + cc4 + j];
      unsigned short hh = f2h(v);
      h[j] = hh; lo[j] = f2h(v - h2f(hh));
    }
    size_t o = (size_t)(u0+uu)*C_ + c0 + cc4;
    *(ushort4*)&th_[o] = make_ushort4(h[0], h[1], h[2], h[3]);
    *(ushort4*)&tl_[o] = make_ushort4(lo[0], lo[1], lo[2], lo[3]);
  }
}

// ---------------- covariance raw sums via 3-term fp16 MFMA, split-K ----------------
__global__ __launch_bounds__(512) void k_covmm(const unsigned short* sp, float* covp) {
  __shared__ unsigned short sm[4*128*LSTR];   // 40960 B
  const int P = 128*LSTR;
  int t = threadIdx.x;
  int kc = blockIdx.x, m = blockIdx.z;
  int ti = blockIdx.y >> 1, tj = blockIdx.y & 1;
  const unsigned short* Xh = sp + (size_t)m * 2 * (size_t)CN;
  const unsigned short* Xl = Xh + CN;
  int v0 = ti * 128, u0 = tj * 128;
  int wave = t >> 6, lane = t & 63;
  int wv = wave >> 1, wu = wave & 1;
  int lx16 = lane & 15, quad = lane >> 4;
  int srow = t >> 2, sseg = (t & 3) * 8;
  f32x4 acc[2][4];
#pragma unroll
  for (int i = 0; i < 2; i++)
#pragma unroll
    for (int j = 0; j < 4; j++) acc[i][j] = (f32x4){0.f, 0.f, 0.f, 0.f};

  int kbeg = kc * (N_ / KSPLIT), kend = kbeg + (N_ / KSPLIT);
  for (int k0 = kbeg; k0 < kend; k0 += 32) {
    __syncthreads();
    {
      size_t goA = (size_t)(v0 + srow) * N_ + k0 + sseg;
      size_t goB = (size_t)(u0 + srow) * N_ + k0 + sseg;
      int lo_ = srow * LSTR + sseg;
      *(float4*)&sm[0*P + lo_] = *(const float4*)&Xh[goA];
      *(float4*)&sm[1*P + lo_] = *(const float4*)&Xl[goA];
      *(float4*)&sm[2*P + lo_] = *(const float4*)&Xh[goB];
      *(float4*)&sm[3*P + lo_] = *(const float4*)&Xl[goB];
    }
    __syncthreads();
#pragma unroll
    for (int mt = 0; mt < 2; mt++) {
      int arow = (wv*32 + mt*16 + lx16)*LSTR + quad*8;
      f16x8 ah = *(const f16x8*)&sm[0*P + arow];
      f16x8 al = *(const f16x8*)&sm[1*P + arow];
#pragma unroll
      for (int nt = 0; nt < 4; nt++) {
        int brow = (wu*64 + nt*16 + lx16)*LSTR + quad*8;
        f16x8 bh = *(const f16x8*)&sm[2*P + brow];
        f16x8 bl = *(const f16x8*)&sm[3*P + brow];
        f32x4 a = acc[mt][nt];
        a = __builtin_amdgcn_mfma_f32_16x16x32_f16(ah, bh, a, 0, 0, 0);
        a = __builtin_amdgcn_mfma_f32_16x16x32_f16(ah, bl, a, 0, 0, 0);
        a = __builtin_amdgcn_mfma_f32_16x16x32_f16(al, bh, a, 0, 0, 0);
        acc[mt][nt] = a;
      }
    }
  }
  float* O = covp + ((size_t)kc*4 + m) * 65536;
#pragma unroll
  for (int mt = 0; mt < 2; mt++)
#pragma unroll
    for (int nt = 0; nt < 4; nt++)
#pragma unroll
      for (int i = 0; i < 4; i++)
        O[(size_t)(v0 + wv*32 + mt*16 + quad*4 + i)*C_ + (u0 + wu*64 + nt*16 + lx16)] =
            acc[mt][nt][i];
}

// ---------------- trace from partials -> cnrm = (tr/256)*1.3 ----------------
__global__ __launch_bounds__(256) void k_trace2(const float* covp, const float* means,
                                                float* cnrm) {
  int m = blockIdx.x, t = threadIdx.x;
  float s = 0.f;
#pragma unroll
  for (int kc = 0; kc < KSPLIT; kc++)
    s += covp[((size_t)kc*4 + m)*65536 + (size_t)t*257];
  float mi = means[m*C_ + t];
  float d = (s - (float)N_*mi*mi) * (1.f/(float)(N_-1));
  __shared__ float red[256];
  red[t] = d; __syncthreads();
  for (int off = 128; off > 0; off >>= 1) { if (t < off) red[t] += red[t + off]; __syncthreads(); }
  if (!t) cnrm[m] = red[0] * (1.3f/256.f);
}

// ---------------- merged covred + nsinit ----------------
__global__ __launch_bounds__(256) void k_covred_init(const float* covp, const float* means,
                                                     const float* cnrm, float* Y, float* Z) {
  int i = blockIdx.x, m = blockIdx.y, j = threadIdx.x;
  float s = 0.f;
#pragma unroll
  for (int kc = 0; kc < KSPLIT; kc++)
    s += covp[((size_t)kc*4 + m)*65536 + (size_t)i*C_ + j];
  float mi = means[m*C_ + i], mj = means[m*C_ + j];
  float cv = (s - (float)N_*mi*mj) * (1.f/(float)(N_-1));
  size_t o = (size_t)m*65536 + (size_t)i*C_ + j;
  Y[o] = cv / cnrm[m];
  Z[o] = (i == j) ? 1.f : 0.f;
}

// ---------------- NS phase A (MFMA, 32x32 tiles): T = 3I - Z·Y^T ----------------
__global__ __launch_bounds__(256) void k_nsA(const float* Zin, const float* Yin, float* T) {
  __shared__ unsigned short sm[4*32*LSTR];   // 10240 B
  int m = blockIdx.y;
  int m0 = (blockIdx.x >> 3) * 32, n0 = (blockIdx.x & 7) * 32;
  const float* A = Zin + (size_t)m*65536;
  const float* B = Yin + (size_t)m*65536;
  float* O = T + (size_t)m*65536;
  f32x4 acc = mm32_3term(sm, A, B, m0, n0);
  int t = threadIdx.x, lane = t & 63;
  int w = t >> 6, wv = w >> 1, wu = w & 1;
  int lx16 = lane & 15, quad = lane >> 4;
#pragma unroll
  for (int i = 0; i < 4; i++) {
    int r = m0 + wv*16 + quad*4 + i;
    int c = n0 + wu*16 + lx16;
    float v = acc[i];
    O[(size_t)r*256 + c] = (r == c) ? 3.f - v : -v;
  }
}

// ---------------- NS phase B (MFMA, 32x32 tiles) ----------------
__global__ __launch_bounds__(256) void k_nsB(const float* Yin, const float* Zin, const float* T,
                                             float* Yout, float* Zout) {
  __shared__ unsigned short sm[4*32*LSTR];
  int m = blockIdx.y, z = blockIdx.z;
  const float* A = (z == 0 ? Yin : Zin) + (size_t)m*65536;
  const float* B = T + (size_t)m*65536;
  float* O = (z == 0 ? Yout : Zout) + (size_t)m*65536;
  int m0 = (blockIdx.x >> 3) * 32, n0 = (blockIdx.x & 7) * 32;
  f32x4 acc = mm32_3term(sm, A, B, m0, n0);
  int t = threadIdx.x, lane = t & 63;
  int w = t >> 6, wv = w >> 1, wu = w & 1;
  int lx16 = lane & 15, quad = lane >> 4;
#pragma unroll
  for (int i = 0; i < 4; i++) {
    int r = m0 + wv*16 + quad*4 + i;
    int c = n0 + wu*16 + lx16;
    O[(size_t)r*256 + c] = 0.5f * acc[i];
  }
}

// ---------------- whiten via MFMA, writing whitened TRANSPOSED fp16 planes directly ----------
__global__ __launch_bounds__(256) void k_whitenT(const unsigned short* xcT, const float* Zall,
                                                 const float* cnrm, unsigned short* outT) {
  __shared__ unsigned short sm[4*64*LSTR];   // 20480 B; epilogue Th/Tl [64][72] unioned
  const int P = 64*LSTR;
  int m = blockIdx.z;
  int v0 = blockIdx.x * 64, c0 = blockIdx.y * 64;
  const float* Zm = Zall + (size_t)m*65536;
  const unsigned short* Bh_g = xcT + (size_t)(2*m+0)*CN;
  const unsigned short* Bl_g = xcT + (size_t)(2*m+1)*CN;
  unsigned short* Oh = outT + (size_t)(2*m+0)*CN;
  unsigned short* Ol = outT + (size_t)(2*m+1)*CN;
  int t = threadIdx.x, lane = t & 63;
  int wv = (t >> 7) & 1, wu = (t >> 6) & 1;
  int lx16 = lane & 15, quad = lane >> 4;
  int srow = t >> 2, sseg = (t & 3) * 8;
  f32x4 acc[2][2];
#pragma unroll
  for (int i = 0; i < 2; i++)
#pragma unroll
    for (int j = 0; j < 2; j++) acc[i][j] = (f32x4){0.f, 0.f, 0.f, 0.f};
  for (int k0 = 0; k0 < 256; k0 += 32) {
    __syncthreads();
    {
      const float* pa = &Zm[(size_t)(c0 + srow)*256 + k0 + sseg];
      int lo_ = srow*LSTR + sseg;
#pragma unroll
      for (int g = 0; g < 2; g++) {
        float4 va = *(const float4*)(pa + g*4);
        float fa[4] = {va.x, va.y, va.z, va.w};
        unsigned short ha[4], la[4];
#pragma unroll
        for (int j = 0; j < 4; j++) {
          unsigned short h = f2h(fa[j]); ha[j] = h; la[j] = f2h(fa[j] - h2f(h));
        }
        *(ushort4*)&sm[0*P + lo_ + g*4] = make_ushort4(ha[0], ha[1], ha[2], ha[3]);
        *(ushort4*)&sm[1*P + lo_ + g*4] = make_ushort4(la[0], la[1], la[2], la[3]);
      }
      size_t gb = (size_t)(v0 + srow)*C_ + k0 + sseg;
      *(float4*)&sm[2*P + lo_] = *(const float4*)&Bh_g[gb];
      *(float4*)&sm[3*P + lo_] = *(const float4*)&Bl_g[gb];
    }
    __syncthreads();
    f16x8 ah[2], al[2], bh[2], bl[2];
#pragma unroll
    for (int mt = 0; mt < 2; mt++) {
      int arow = (wv*32 + mt*16 + lx16)*LSTR + quad*8;
      ah[mt] = *(const f16x8*)&sm[0*P + arow];
      al[mt] = *(const f16x8*)&sm[1*P + arow];
    }
#pragma unroll
    for (int nt = 0; nt < 2; nt++) {
      int brow = (wu*32 + nt*16 + lx16)*LSTR + quad*8;
      bh[nt] = *(const f16x8*)&sm[2*P + brow];
      bl[nt] = *(const f16x8*)&sm[3*P + brow];
    }
#pragma unroll
    for (int mt = 0; mt < 2; mt++)
#pragma unroll
      for (int nt = 0; nt < 2; nt++) {
        f32x4 a = acc[mt][nt];
        a = __builtin_amdgcn_mfma_f32_16x16x32_f16(ah[mt], bh[nt], a, 0, 0, 0);
        a = __builtin_amdgcn_mfma_f32_16x16x32_f16(ah[mt], bl[nt], a, 0, 0, 0);
        a = __builtin_amdgcn_mfma_f32_16x16x32_f16(al[mt], bh[nt], a, 0, 0, 0);
        acc[mt][nt] = a;
      }
  }
  float scale = 1.0f / sqrtf(cnrm[m]);
  __syncthreads();
  unsigned short* Th = sm;             // [64][72]
  unsigned short* Tl = sm + 64*72;
#pragma unroll
  for (int mt = 0; mt < 2; mt++)
#pragma unroll
    for (int nt = 0; nt < 2; nt++)
#pragma unroll
      for (int i = 0; i < 4; i++) {
        int chl = wv*32 + mt*16 + quad*4 + i;
        int vl  = wu*32 + nt*16 + lx16;
        float ww = acc[mt][nt][i] * scale;
        unsigned short h = f2h(ww);
        unsigned short l = f2h(ww - h2f(h));
        Th[vl*72 + chl] = h;
        Tl[vl*72 + chl] = l;
      }
  __syncthreads();
  int vr = t >> 2, cs = (t & 3) * 16;
  size_t go = (size_t)(v0 + vr)*C_ + c0 + cs;
  *(float4*)&Oh[go]     = *(float4*)&Th[vr*72 + cs];
  *(float4*)&Oh[go + 8] = *(float4*)&Th[vr*72 + cs + 8];
  *(float4*)&Ol[go]     = *(float4*)&Tl[vr*72 + cs];
  *(float4*)&Ol[go + 8] = *(float4*)&Tl[vr*72 + cs + 8];
}

// ---------------- per-pixel channel sum-of-squares from whitened planes ----------------
__global__ __launch_bounds__(256) void k_ssq(const unsigned short* outT, float* ssq) {
  int b = blockIdx.y; int p = blockIdx.x * 256 + threadIdx.x;
  const unsigned short* h = outT + (size_t)(2*(2+b))*CN + (size_t)p*C_;
  const unsigned short* l = h + CN;
  float acc = 0.f;
  for (int c = 0; c < C_; c += 4) {
    ushort4 hv = *(const ushort4*)&h[c];
    ushort4 lv = *(const ushort4*)&l[c];
    float v0 = h2f(hv.x) + h2f(lv.x);
    float v1 = h2f(hv.y) + h2f(lv.y);
    float v2 = h2f(hv.z) + h2f(lv.z);
    float v3 = h2f(hv.w) + h2f(lv.w);
    acc += v0*v0 + v1*v1 + v2*v2 + v3*v3;
  }
  ssq[b*N_ + p] = acc;
}

// ---------------- patch reciprocal norms ----------------
__global__ __launch_bounds__(256) void k_rnorm(const float* ssq, float* rnorm) {
  int b = blockIdx.y; int s = blockIdx.x * 256 + threadIdx.x;
  int sy = s >> 6, sx = s & 63;
  float sum = 0.f;
#pragma unroll
  for (int ky = 0; ky < 3; ky++)
#pragma unroll
    for (int kx = 0; kx < 3; kx++)
      sum += ssq[b*N_ + refl(sy+ky-1)*64 + refl(sx+kx-1)];
  rnorm[b*N_ + s] = 1.f / (sqrtf(sum) + EPSF);
}

// ---------------- Gram via 2-way-split fp16 MFMA + fused x-blur ----------------
__global__ __launch_bounds__(512) void k_gram(const unsigned short* Ah_g, const unsigned short* Al_g,
                                              const unsigned short* Bh_g, const unsigned short* Bl_g,
                                              float* Hx) {
  __shared__ unsigned short sm[4*128*LSTR];  // 40960 B; epilogue Gs[64][133] fp32 unioned
  const int P = 128*LSTR;
  int t = threadIdx.x;
  int v0 = blockIdx.y * 128, u0 = blockIdx.x * 128;
  int wave = t >> 6, lane = t & 63;
  int wv = wave >> 1, wu = wave & 1;
  int lx16 = lane & 15, quad = lane >> 4;
  int srow = t >> 2, sseg = (t & 3) * 8;
  f32x4 acc[2][4];
#pragma unroll
  for (int i = 0; i < 2; i++)
#pragma unroll
    for (int j = 0; j < 4; j++) acc[i][j] = (f32x4){0.f, 0.f, 0.f, 0.f};

  for (int k0 = 0; k0 < 256; k0 += 32) {
    __syncthreads();
    {
      size_t goA = (size_t)(v0 + srow)*C_ + k0 + sseg;
      size_t goB = (size_t)(u0 + srow)*C_ + k0 + sseg;
      int lo_ = srow*LSTR + sseg;
      *(float4*)&sm[0*P + lo_] = *(const float4*)&Ah_g[goA];
      *(float4*)&sm[1*P + lo_] = *(const float4*)&Al_g[goA];
      *(float4*)&sm[2*P + lo_] = *(const float4*)&Bh_g[goB];
      *(float4*)&sm[3*P + lo_] = *(const float4*)&Bl_g[goB];
    }
    __syncthreads();
    int kb = quad*8;
    f16x8 ah[2], al[2];
#pragma unroll
    for (int mt = 0; mt < 2; mt++) {
      int arow = (wv*32 + mt*16 + lx16)*LSTR + kb;
      ah[mt] = *(const f16x8*)&sm[0*P + arow];
      al[mt] = *(const f16x8*)&sm[1*P + arow];
    }
    f16x8 bh[4], bl[4];
#pragma unroll
    for (int nt = 0; nt < 4; nt++) {
      int brow = (wu*64 + nt*16 + lx16)*LSTR + kb;
      bh[nt] = *(const f16x8*)&sm[2*P + brow];
      bl[nt] = *(const f16x8*)&sm[3*P + brow];
    }
#pragma unroll
    for (int mt = 0; mt < 2; mt++)
#pragma unroll
      for (int nt = 0; nt < 4; nt++) {
        f32x4 a = acc[mt][nt];
        a = __builtin_amdgcn_mfma_f32_16x16x32_f16(ah[mt], bh[nt], a, 0, 0, 0);
        a = __builtin_amdgcn_mfma_f32_16x16x32_f16(ah[mt], bl[nt], a, 0, 0, 0);
        a = __builtin_amdgcn_mfma_f32_16x16x32_f16(al[mt], bh[nt], a, 0, 0, 0);
        acc[mt][nt] = a;
      }
  }
  float* Gs = (float*)sm;
  int btx = t & 15, bty = t >> 4;
#pragma unroll
  for (int h = 0; h < 2; h++) {
    __syncthreads();
    if ((wv >> 1) == h) {
      int rbase = (wv & 1) * 32;
#pragma unroll
      for (int mt = 0; mt < 2; mt++)
#pragma unroll
        for (int nt = 0; nt < 4; nt++)
#pragma unroll
          for (int i = 0; i < 4; i++)
            Gs[(rbase + mt*16 + quad*4 + i)*133 + wu*64 + nt*16 + lx16] = acc[mt][nt][i];
    }
    __syncthreads();
#pragma unroll
    for (int i = 0; i < 2; i++) {
      int px = bty + 32*i;                 // bank-spread remap
      int xm = refl(px-1), xp = refl(px+1);
#pragma unroll
      for (int jh = 0; jh < 2; jh++) {
        int ub = jh*64;
        float tmp[4];
#pragma unroll
        for (int j = 0; j < 4; j++) {
          int sx = btx*4 + j;
          int smm = refl(sx-1), sp = refl(sx+1);
          tmp[j] = Gs[xm*133 + ub + smm] + Gs[px*133 + ub + sx] + Gs[xp*133 + ub + sp];
        }
        *(float4*)&Hx[(size_t)(v0 + h*64 + px)*N_ + u0 + ub + btx*4] =
            make_float4(tmp[0], tmp[1], tmp[2], tmp[3]);
      }
    }
  }
}

// ---------------- y-diagonal blur of Hx + argmax (8-row grouping + shuffle reduction) -------
// 10 Hx rows per 8 outputs (1.25x Hx traffic). Reduction: wave-level __shfl_down of all 8
// candidates (no barriers), then one cross-wave merge (2 barriers total, was ~40).
__global__ __launch_bounds__(256) void k_argmax(const float* Hx, const float* rnorm,
                                                int* idx, int b) {
  int blk = blockIdx.x, t = threadIdx.x;
  int q = blk >> 6, px = blk & 63;     // grid 512: q 0..7
  int py0 = 8*q;
  size_t R[10];
  R[0] = (size_t)(refl(py0-1)*64 + px) * N_;
#pragma unroll
  for (int j = 0; j < 8; j++) R[j+1] = (size_t)((py0+j)*64 + px) * N_;
  R[9] = (size_t)(refl(py0+8)*64 + px) * N_;
  float bv[8];
  int bs[8];
#pragma unroll
  for (int j = 0; j < 8; j++) { bv[j] = -1e30f; bs[j] = 0; }
  for (int s = t; s < N_; s += 256) {
    int sy = s >> 6, sx = s & 63;
    int u0 = refl(sy-1)*64 + sx, u2 = refl(sy+1)*64 + sx;
    float rn = rnorm[b*N_ + s];
#pragma unroll
    for (int j = 0; j < 8; j++) {
      float a = Hx[R[j] + u0] + Hx[R[j+1] + s] + Hx[R[j+2] + u2];
      float sc = a * rn;
      if (sc > bv[j]) { bv[j] = sc; bs[j] = s; }
    }
  }
  // wave-level reduce (64 lanes), all 8 candidates in parallel, no barriers
  int lane = t & 63, wave = t >> 6;
#pragma unroll
  for (int off = 32; off > 0; off >>= 1) {
#pragma unroll
    for (int j = 0; j < 8; j++) {
      float ov = __shfl_down(bv[j], off);
      int   oi = __shfl_down(bs[j], off);
      if (ov > bv[j] || (ov == bv[j] && oi < bs[j])) { bv[j] = ov; bs[j] = oi; }
    }
  }
  __shared__ float swv[4][8];
  __shared__ int   swi[4][8];
  if (lane == 0)
#pragma unroll
    for (int j = 0; j < 8; j++) { swv[wave][j] = bv[j]; swi[wave][j] = bs[j]; }
  __syncthreads();
  if (t < 8) {
    float v = swv[0][t]; int ii = swi[0][t];
#pragma unroll
    for (int w = 1; w < 4; w++) {
      if (swv[w][t] > v || (swv[w][t] == v && swi[w][t] < ii)) { v = swv[w][t]; ii = swi[w][t]; }
    }
    idx[b*N_ + (py0 + t)*64 + px] = ii;
  }
}

// ---------------- deconv gather for batch b: 2 channels/thread via uint loads ----------------
// 2 pixels per 256-thread block (grid 2048): thread handles channels (c0, c0+1) of pixel
// p = 2*blk + (t>>7) with 4B loads — halves load instruction count vs scalar ushort.
__global__ __launch_bounds__(256) void k_recon(const unsigned short* nsTh,
                                               const unsigned short* nsTl,
                                               const int* idx_b, float* recont_b) {
  int t = threadIdx.x;
  int p = blockIdx.x * 2 + (t >> 7);
  int c0 = (t & 127) * 2;
  int py = p >> 6, px = p & 63;
  float a0 = 0.f, a1 = 0.f;
#pragma unroll
  for (int dy = 0; dy < 3; dy++)
#pragma unroll
    for (int dx = 0; dx < 3; dx++) {
      int q = refl(py+dy-1)*64 + refl(px+dx-1);
      int s = idx_b[q];
      int sy = s >> 6, sx = s & 63;
      size_t o = (size_t)(refl(sy+1-dy)*64 + refl(sx+1-dx))*C_ + c0;
      unsigned hv = *(const unsigned*)&nsTh[o];
      unsigned lv = *(const unsigned*)&nsTl[o];
      a0 += h2f((unsigned short)(hv & 0xffff)) + h2f((unsigned short)(lv & 0xffff));
      a1 += h2f((unsigned short)(hv >> 16))    + h2f((unsigned short)(lv >> 16));
    }
  float dc = ((py==0||py==63)?2.f:3.f) * ((px==0||px==63)?2.f:3.f);
  float rdc = 1.f / dc;
  *(float2*)&recont_b[(size_t)p*C_ + c0] = make_float2(a0 * rdc, a1 * rdc);
}

// ---------------- coloring (MFMA): out = Ym·recont^T ----------------
__global__ __launch_bounds__(256) void k_color(const float* Yall, const float* recont_all,
                                               const float* cnrm, const float* means,
                                               float* out_all) {
  __shared__ unsigned short sm[4*64*LSTR];
  int b = blockIdx.z;
  const float* Ym = Yall + (size_t)(2+b)*65536;
  const float* recont = recont_all + (size_t)b*CN;   // [4096][256]
  const float* smean = means + (2+b)*C_;
  float* out = out_all + (size_t)b*CN;               // [256][4096]
  int m0 = blockIdx.y * 64;
  int n0 = blockIdx.x * 64;
  f32x4 acc[2][2];
  mm64_3term(sm, Ym, recont, m0, n0, acc);
  float scale = sqrtf(cnrm[2+b]);
  int t = threadIdx.x, lane = t & 63;
  int wv = (t >> 7) & 1, wu = (t >> 6) & 1, lx16 = lane & 15, quad = lane >> 4;
#pragma unroll
  for (int mt = 0; mt < 2; mt++)
#pragma unroll
    for (int nt = 0; nt < 2; nt++)
#pragma unroll
      for (int i = 0; i < 4; i++) {
        int r = m0 + wv*32 + mt*16 + quad*4 + i;
        int c = n0 + wu*32 + nt*16 + lx16;
        out[(size_t)r*N_ + c] = acc[mt][nt][i]*scale + smean[r];
      }
}

extern "C" void kernel_launch(void* const* d_in, const int* in_sizes, int n_in,
                              void* d_out, int out_size, void* d_ws, size_t ws_size,
                              hipStream_t stream) {
  const float* content = (const float*)d_in[0];
  const float* style   = (const float*)d_in[1];
  float* out = (float*)d_out;

  // workspace layout (floats); total ~102 MiB
  float* F = (float*)d_ws;
  float* means  = F + 0;         // 4*256
  float* cnrm   = F + 1024;      // 4
  float* Y      = F + 264192;    // NS buffers
  float* Z      = F + 526336;
  float* Y2     = F + 788480;
  float* Z2     = F + 1050624;
  float* T      = F + 1312768;
  float* ncreg  = F + 1574912;   // outT (8 fp16 plane slots, 16 MB)
  float* nsreg  = F + 3672064;   // xcT  (8 fp16 plane slots, 16 MB)
  float* recont = F + 7866368;   // 2*CN fp32
  float* ssq    = F + 9963520;   // 2*4096
  float* rnorm  = F + 9971712;   // 2*4096
  int*   idx    = (int*)(F + 9979904); // 2*4096
  float* Hx     = F + 9988096;   // 4096*4096 (16.7M floats)

  // cov-phase aliases inside Hx (dead until k_gram at step 8):
  //  covsp = 16.8 MB = 4.19M floats; covp = KSPLIT(32)*4*65536 = 8.39M floats -> ends
  //  at Hx+12.6M < 16.7M  ✓
  unsigned short* covsp = (unsigned short*)Hx;
  float* covp = Hx + 4194304;

  unsigned short* xcT  = (unsigned short*)nsreg;
  unsigned short* outT = (unsigned short*)ncreg;

  // 1-4. means, fused split, MFMA cov partials, trace, covred+nsinit
  k_mean<<<dim3(256,4), 256, 0, stream>>>(content, style, means);
  k_splitall<<<dim3(128,8,4), 256, 0, stream>>>(content, style, means, covsp, xcT);
  k_covmm<<<dim3(KSPLIT,4,4), 512, 0, stream>>>(covsp, covp);
  k_trace2<<<4, 256, 0, stream>>>(covp, means, cnrm);
  k_covred_init<<<dim3(256,4), 256, 0, stream>>>(covp, means, cnrm, Y, Z);
  // 5. NS iterations (separate launches — cooperative grid.sync measured 20x worse, r8)
  float *Ya = Y, *Za = Z, *Yb = Y2, *Zb = Z2;
  for (int it = 0; it < NS_ITERS; it++) {
    k_nsA<<<dim3(64,4), 256, 0, stream>>>(Za, Ya, T);
    k_nsB<<<dim3(64,4,2), 256, 0, stream>>>(Ya, Za, T, Yb, Zb);
    float* tmp;
    tmp = Ya; Ya = Yb; Yb = tmp;
    tmp = Za; Za = Zb; Zb = tmp;
  }
  // 6. whitening (MFMA) -> whitened transposed fp16 planes directly
  k_whitenT<<<dim3(64,4,4), 256, 0, stream>>>(xcT, Za, cnrm, outT);
  // 7. patch norms from planes
  k_ssq<<<dim3(16,2), 256, 0, stream>>>(outT, ssq);
  k_rnorm<<<dim3(16,2), 256, 0, stream>>>(ssq, rnorm);
  // 8. per batch: MFMA gram + x-blur -> 8-row y-blur+argmax -> recon
  for (int b = 0; b < 2; b++) {
    k_gram<<<dim3(32,32), 512, 0, stream>>>(outT + (size_t)(2*b)*CN,
                                            outT + (size_t)(2*b+1)*CN,
                                            outT + (size_t)(2*(2+b))*CN,
                                            outT + (size_t)(2*(2+b)+1)*CN, Hx);
    k_argmax<<<512, 256, 0, stream>>>(Hx, rnorm, idx, b);
    k_recon<<<2048, 256, 0, stream>>>(outT + (size_t)(2*(2+b))*CN,
                                      outT + (size_t)(2*(2+b)+1)*CN,
                                      idx + (size_t)b*N_, recont + (size_t)b*CN);
  }
  // 9. coloring (MFMA)
  k_color<<<dim3(64,4,2), 256, 0, stream>>>(Ya, recont, cnrm, means, out);
}

// Round 11
// 342.934 us; speedup vs baseline: 1.0439x; 1.0439x over previous
//
#include <hip/hip_runtime.h>
#include <hip/hip_bf16.h>

#define C_ 256
#define N_ 4096
#define CN (C_*N_)
#define EPSF 1e-5f
#define NS_ITERS 6
#define KSPLIT 32  // split-K for MFMA cov partials (512 blocks = 2/CU)
#define LSTR 40   // LDS row stride in ushort (80 B, 16B-aligned)

typedef _Float16 f16x8 __attribute__((ext_vector_type(8)));
typedef float f32x4 __attribute__((ext_vector_type(4)));

__device__ __forceinline__ int refl(int t) {
  return t < 0 ? -t : (t > 63 ? 126 - t : t);
}

// fp16 2-way split: v = h + l exact to ~2^-22 rel.
__device__ __forceinline__ unsigned short f2h(float x) {
  _Float16 h = (_Float16)x;
  return __builtin_bit_cast(unsigned short, h);
}
__device__ __forceinline__ float h2f(unsigned short u) {
  return (float)__builtin_bit_cast(_Float16, u);
}

// ---------------- shared MFMA helper: 64x64 out tile of A·B^T, K=256, fp32 in ----------------
__device__ __forceinline__ void mm64_3term(unsigned short* sm, const float* A, const float* B,
                                           int m0, int n0, f32x4 acc[2][2]) {
  const int P = 64*LSTR;
  int t = threadIdx.x;
  int lane = t & 63;
  int wv = (t >> 7) & 1, wu = (t >> 6) & 1;
  int lx16 = lane & 15, quad = lane >> 4;
  int srow = t >> 2, sseg = (t & 3) * 8;
#pragma unroll
  for (int i = 0; i < 2; i++)
#pragma unroll
    for (int j = 0; j < 2; j++) acc[i][j] = (f32x4){0.f, 0.f, 0.f, 0.f};
  for (int k0 = 0; k0 < 256; k0 += 32) {
    __syncthreads();
    {
      const float* pa = &A[(size_t)(m0 + srow)*256 + k0 + sseg];
      const float* pb = &B[(size_t)(n0 + srow)*256 + k0 + sseg];
#pragma unroll
      for (int g = 0; g < 2; g++) {
        float4 va = *(const float4*)(pa + g*4);
        float4 vb = *(const float4*)(pb + g*4);
        float fa[4] = {va.x, va.y, va.z, va.w};
        float fb[4] = {vb.x, vb.y, vb.z, vb.w};
        unsigned short ha[4], la[4], hb[4], lb[4];
#pragma unroll
        for (int j = 0; j < 4; j++) {
          unsigned short h = f2h(fa[j]); ha[j] = h; la[j] = f2h(fa[j] - h2f(h));
          h = f2h(fb[j]); hb[j] = h; lb[j] = f2h(fb[j] - h2f(h));
        }
        int lo_ = srow*LSTR + sseg + g*4;
        *(ushort4*)&sm[0*P + lo_] = make_ushort4(ha[0], ha[1], ha[2], ha[3]);
        *(ushort4*)&sm[1*P + lo_] = make_ushort4(la[0], la[1], la[2], la[3]);
        *(ushort4*)&sm[2*P + lo_] = make_ushort4(hb[0], hb[1], hb[2], hb[3]);
        *(ushort4*)&sm[3*P + lo_] = make_ushort4(lb[0], lb[1], lb[2], lb[3]);
      }
    }
    __syncthreads();
    f16x8 ah[2], al[2], bh[2], bl[2];
#pragma unroll
    for (int mt = 0; mt < 2; mt++) {
      int arow = (wv*32 + mt*16 + lx16)*LSTR + quad*8;
      ah[mt] = *(const f16x8*)&sm[0*P + arow];
      al[mt] = *(const f16x8*)&sm[1*P + arow];
    }
#pragma unroll
    for (int nt = 0; nt < 2; nt++) {
      int brow = (wu*32 + nt*16 + lx16)*LSTR + quad*8;
      bh[nt] = *(const f16x8*)&sm[2*P + brow];
      bl[nt] = *(const f16x8*)&sm[3*P + brow];
    }
#pragma unroll
    for (int mt = 0; mt < 2; mt++)
#pragma unroll
      for (int nt = 0; nt < 2; nt++) {
        f32x4 a = acc[mt][nt];
        a = __builtin_amdgcn_mfma_f32_16x16x32_f16(ah[mt], bh[nt], a, 0, 0, 0);
        a = __builtin_amdgcn_mfma_f32_16x16x32_f16(ah[mt], bl[nt], a, 0, 0, 0);
        a = __builtin_amdgcn_mfma_f32_16x16x32_f16(al[mt], bh[nt], a, 0, 0, 0);
        acc[mt][nt] = a;
      }
  }
}

// ---------------- mm32: 32x32 out tile of A·B^T, K=256, fp32 in (NS parallelism) ----------
__device__ __forceinline__ f32x4 mm32_3term(unsigned short* sm, const float* A, const float* B,
                                            int m0, int n0) {
  const int P = 32*LSTR;
  int t = threadIdx.x, lane = t & 63;
  int w = t >> 6, wv = w >> 1, wu = w & 1;
  int lx16 = lane & 15, quad = lane >> 4;
  int mat = t >> 7, srow = (t >> 2) & 31, sseg = (t & 3) * 8;
  const float* S = mat ? B : A;
  int rb = mat ? n0 : m0;
  int base0 = mat ? 2*P : 0;
  f32x4 acc = (f32x4){0.f, 0.f, 0.f, 0.f};
  for (int k0 = 0; k0 < 256; k0 += 32) {
    __syncthreads();
    {
      const float* p = &S[(size_t)(rb + srow)*256 + k0 + sseg];
      int lo_ = srow*LSTR + sseg;
#pragma unroll
      for (int g = 0; g < 2; g++) {
        float4 v = *(const float4*)(p + g*4);
        float f[4] = {v.x, v.y, v.z, v.w};
        unsigned short hh[4], ll[4];
#pragma unroll
        for (int j = 0; j < 4; j++) {
          unsigned short h = f2h(f[j]); hh[j] = h; ll[j] = f2h(f[j] - h2f(h));
        }
        *(ushort4*)&sm[base0 + lo_ + g*4]     = make_ushort4(hh[0], hh[1], hh[2], hh[3]);
        *(ushort4*)&sm[base0 + P + lo_ + g*4] = make_ushort4(ll[0], ll[1], ll[2], ll[3]);
      }
    }
    __syncthreads();
    int arow = (wv*16 + lx16)*LSTR + quad*8;
    int brow = (wu*16 + lx16)*LSTR + quad*8;
    f16x8 ah = *(const f16x8*)&sm[0*P + arow];
    f16x8 al = *(const f16x8*)&sm[1*P + arow];
    f16x8 bh = *(const f16x8*)&sm[2*P + brow];
    f16x8 bl = *(const f16x8*)&sm[3*P + brow];
    acc = __builtin_amdgcn_mfma_f32_16x16x32_f16(ah, bh, acc, 0, 0, 0);
    acc = __builtin_amdgcn_mfma_f32_16x16x32_f16(ah, bl, acc, 0, 0, 0);
    acc = __builtin_amdgcn_mfma_f32_16x16x32_f16(al, bh, acc, 0, 0, 0);
  }
  return acc;
}

// ---------------- means (float4-vectorized) ----------------
__global__ __launch_bounds__(256) void k_mean(const float* content, const float* style,
                                              float* means) {
  int c = blockIdx.x, m = blockIdx.y, t = threadIdx.x;
  const float* x = (m < 2 ? content : style) + (size_t)(m & 1) * CN + (size_t)c * N_;
  const float4* x4 = (const float4*)x;
  float s = 0.f;
#pragma unroll
  for (int i = 0; i < 4; i++) {
    float4 v = x4[t + i*256];
    s += v.x + v.y + v.z + v.w;
  }
  __shared__ float red[256];
  red[t] = s; __syncthreads();
  for (int off = 128; off > 0; off >>= 1) { if (t < off) red[t] += red[t + off]; __syncthreads(); }
  if (t == 0) means[m * C_ + c] = red[0] * (1.f / N_);
}

// ---------------- fused split: raw [c][n] planes for cov + mean-sub transposed [v][c] planes ----
__global__ __launch_bounds__(256) void k_splitall(const float* content, const float* style,
                                                  const float* means,
                                                  unsigned short* covsp, unsigned short* xcT) {
  int m = blockIdx.z;
  const float* x = (m < 2 ? content : style) + (size_t)(m & 1) * CN;
  int u0 = blockIdx.x * 32, c0 = blockIdx.y * 32;
  unsigned short* ch_ = covsp + (size_t)(2*m+0)*CN;
  unsigned short* cl_ = covsp + (size_t)(2*m+1)*CN;
  unsigned short* th_ = xcT + (size_t)(2*m+0)*CN;
  unsigned short* tl_ = xcT + (size_t)(2*m+1)*CN;
  __shared__ float tile[32][33];
  int t = threadIdx.x;
  {
    int cc = t >> 3, uu4 = (t & 7) * 4;
    float4 v = *(const float4*)&x[(size_t)(c0+cc)*N_ + u0 + uu4];
    float f[4] = {v.x, v.y, v.z, v.w};
    unsigned short h[4], lo[4];
#pragma unroll
    for (int j = 0; j < 4; j++) {
      unsigned short hh = f2h(f[j]);
      h[j] = hh; lo[j] = f2h(f[j] - h2f(hh));
      tile[cc][uu4+j] = f[j];
    }
    size_t o = (size_t)(c0+cc)*N_ + u0 + uu4;
    *(ushort4*)&ch_[o] = make_ushort4(h[0], h[1], h[2], h[3]);
    *(ushort4*)&cl_[o] = make_ushort4(lo[0], lo[1], lo[2], lo[3]);
  }
  __syncthreads();
  {
    int uu = t >> 3, cc4 = (t & 7) * 4;
    unsigned short h[4], lo[4];
#pragma unroll
    for (int j = 0; j < 4; j++) {
      float v = tile[cc4+j][uu] - means[m*C_ + c0 + cc4 + j];
      unsigned short hh = f2h(v);
      h[j] = hh; lo[j] = f2h(v - h2f(hh));
    }
    size_t o = (size_t)(u0+uu)*C_ + c0 + cc4;
    *(ushort4*)&th_[o] = make_ushort4(h[0], h[1], h[2], h[3]);
    *(ushort4*)&tl_[o] = make_ushort4(lo[0], lo[1], lo[2], lo[3]);
  }
}

// ---------------- covariance raw sums via 3-term fp16 MFMA, split-K ----------------
__global__ __launch_bounds__(512) void k_covmm(const unsigned short* sp, float* covp) {
  __shared__ unsigned short sm[4*128*LSTR];   // 40960 B
  const int P = 128*LSTR;
  int t = threadIdx.x;
  int kc = blockIdx.x, m = blockIdx.z;
  int ti = blockIdx.y >> 1, tj = blockIdx.y & 1;
  const unsigned short* Xh = sp + (size_t)m * 2 * (size_t)CN;
  const unsigned short* Xl = Xh + CN;
  int v0 = ti * 128, u0 = tj * 128;
  int wave = t >> 6, lane = t & 63;
  int wv = wave >> 1, wu = wave & 1;
  int lx16 = lane & 15, quad = lane >> 4;
  int srow = t >> 2, sseg = (t & 3) * 8;
  f32x4 acc[2][4];
#pragma unroll
  for (int i = 0; i < 2; i++)
#pragma unroll
    for (int j = 0; j < 4; j++) acc[i][j] = (f32x4){0.f, 0.f, 0.f, 0.f};

  int kbeg = kc * (N_ / KSPLIT), kend = kbeg + (N_ / KSPLIT);
  for (int k0 = kbeg; k0 < kend; k0 += 32) {
    __syncthreads();
    {
      size_t goA = (size_t)(v0 + srow) * N_ + k0 + sseg;
      size_t goB = (size_t)(u0 + srow) * N_ + k0 + sseg;
      int lo_ = srow * LSTR + sseg;
      *(float4*)&sm[0*P + lo_] = *(const float4*)&Xh[goA];
      *(float4*)&sm[1*P + lo_] = *(const float4*)&Xl[goA];
      *(float4*)&sm[2*P + lo_] = *(const float4*)&Xh[goB];
      *(float4*)&sm[3*P + lo_] = *(const float4*)&Xl[goB];
    }
    __syncthreads();
#pragma unroll
    for (int mt = 0; mt < 2; mt++) {
      int arow = (wv*32 + mt*16 + lx16)*LSTR + quad*8;
      f16x8 ah = *(const f16x8*)&sm[0*P + arow];
      f16x8 al = *(const f16x8*)&sm[1*P + arow];
#pragma unroll
      for (int nt = 0; nt < 4; nt++) {
        int brow = (wu*64 + nt*16 + lx16)*LSTR + quad*8;
        f16x8 bh = *(const f16x8*)&sm[2*P + brow];
        f16x8 bl = *(const f16x8*)&sm[3*P + brow];
        f32x4 a = acc[mt][nt];
        a = __builtin_amdgcn_mfma_f32_16x16x32_f16(ah, bh, a, 0, 0, 0);
        a = __builtin_amdgcn_mfma_f32_16x16x32_f16(ah, bl, a, 0, 0, 0);
        a = __builtin_amdgcn_mfma_f32_16x16x32_f16(al, bh, a, 0, 0, 0);
        acc[mt][nt] = a;
      }
    }
  }
  float* O = covp + ((size_t)kc*4 + m) * 65536;
#pragma unroll
  for (int mt = 0; mt < 2; mt++)
#pragma unroll
    for (int nt = 0; nt < 4; nt++)
#pragma unroll
      for (int i = 0; i < 4; i++)
        O[(size_t)(v0 + wv*32 + mt*16 + quad*4 + i)*C_ + (u0 + wu*64 + nt*16 + lx16)] =
            acc[mt][nt][i];
}

// ---------------- trace from partials -> cnrm = (tr/256)*1.3 ----------------
__global__ __launch_bounds__(256) void k_trace2(const float* covp, const float* means,
                                                float* cnrm) {
  int m = blockIdx.x, t = threadIdx.x;
  float s = 0.f;
#pragma unroll
  for (int kc = 0; kc < KSPLIT; kc++)
    s += covp[((size_t)kc*4 + m)*65536 + (size_t)t*257];
  float mi = means[m*C_ + t];
  float d = (s - (float)N_*mi*mi) * (1.f/(float)(N_-1));
  __shared__ float red[256];
  red[t] = d; __syncthreads();
  for (int off = 128; off > 0; off >>= 1) { if (t < off) red[t] += red[t + off]; __syncthreads(); }
  if (!t) cnrm[m] = red[0] * (1.3f/256.f);
}

// ---------------- merged covred + nsinit ----------------
__global__ __launch_bounds__(256) void k_covred_init(const float* covp, const float* means,
                                                     const float* cnrm, float* Y, float* Z) {
  int i = blockIdx.x, m = blockIdx.y, j = threadIdx.x;
  float s = 0.f;
#pragma unroll
  for (int kc = 0; kc < KSPLIT; kc++)
    s += covp[((size_t)kc*4 + m)*65536 + (size_t)i*C_ + j];
  float mi = means[m*C_ + i], mj = means[m*C_ + j];
  float cv = (s - (float)N_*mi*mj) * (1.f/(float)(N_-1));
  size_t o = (size_t)m*65536 + (size_t)i*C_ + j;
  Y[o] = cv / cnrm[m];
  Z[o] = (i == j) ? 1.f : 0.f;
}

// ---------------- NS phase A (MFMA, 32x32 tiles): T = 3I - Z·Y^T ----------------
__global__ __launch_bounds__(256) void k_nsA(const float* Zin, const float* Yin, float* T) {
  __shared__ unsigned short sm[4*32*LSTR];   // 10240 B
  int m = blockIdx.y;
  int m0 = (blockIdx.x >> 3) * 32, n0 = (blockIdx.x & 7) * 32;
  const float* A = Zin + (size_t)m*65536;
  const float* B = Yin + (size_t)m*65536;
  float* O = T + (size_t)m*65536;
  f32x4 acc = mm32_3term(sm, A, B, m0, n0);
  int t = threadIdx.x, lane = t & 63;
  int w = t >> 6, wv = w >> 1, wu = w & 1;
  int lx16 = lane & 15, quad = lane >> 4;
#pragma unroll
  for (int i = 0; i < 4; i++) {
    int r = m0 + wv*16 + quad*4 + i;
    int c = n0 + wu*16 + lx16;
    float v = acc[i];
    O[(size_t)r*256 + c] = (r == c) ? 3.f - v : -v;
  }
}

// ---------------- NS phase B (MFMA, 32x32 tiles) ----------------
__global__ __launch_bounds__(256) void k_nsB(const float* Yin, const float* Zin, const float* T,
                                             float* Yout, float* Zout) {
  __shared__ unsigned short sm[4*32*LSTR];
  int m = blockIdx.y, z = blockIdx.z;
  const float* A = (z == 0 ? Yin : Zin) + (size_t)m*65536;
  const float* B = T + (size_t)m*65536;
  float* O = (z == 0 ? Yout : Zout) + (size_t)m*65536;
  int m0 = (blockIdx.x >> 3) * 32, n0 = (blockIdx.x & 7) * 32;
  f32x4 acc = mm32_3term(sm, A, B, m0, n0);
  int t = threadIdx.x, lane = t & 63;
  int w = t >> 6, wv = w >> 1, wu = w & 1;
  int lx16 = lane & 15, quad = lane >> 4;
#pragma unroll
  for (int i = 0; i < 4; i++) {
    int r = m0 + wv*16 + quad*4 + i;
    int c = n0 + wu*16 + lx16;
    O[(size_t)r*256 + c] = 0.5f * acc[i];
  }
}

// ---------------- whiten via MFMA, writing whitened TRANSPOSED fp16 planes directly ----------
__global__ __launch_bounds__(256) void k_whitenT(const unsigned short* xcT, const float* Zall,
                                                 const float* cnrm, unsigned short* outT) {
  __shared__ unsigned short sm[4*64*LSTR];   // 20480 B; epilogue Th/Tl [64][72] unioned
  const int P = 64*LSTR;
  int m = blockIdx.z;
  int v0 = blockIdx.x * 64, c0 = blockIdx.y * 64;
  const float* Zm = Zall + (size_t)m*65536;
  const unsigned short* Bh_g = xcT + (size_t)(2*m+0)*CN;
  const unsigned short* Bl_g = xcT + (size_t)(2*m+1)*CN;
  unsigned short* Oh = outT + (size_t)(2*m+0)*CN;
  unsigned short* Ol = outT + (size_t)(2*m+1)*CN;
  int t = threadIdx.x, lane = t & 63;
  int wv = (t >> 7) & 1, wu = (t >> 6) & 1;
  int lx16 = lane & 15, quad = lane >> 4;
  int srow = t >> 2, sseg = (t & 3) * 8;
  f32x4 acc[2][2];
#pragma unroll
  for (int i = 0; i < 2; i++)
#pragma unroll
    for (int j = 0; j < 2; j++) acc[i][j] = (f32x4){0.f, 0.f, 0.f, 0.f};
  for (int k0 = 0; k0 < 256; k0 += 32) {
    __syncthreads();
    {
      const float* pa = &Zm[(size_t)(c0 + srow)*256 + k0 + sseg];
      int lo_ = srow*LSTR + sseg;
#pragma unroll
      for (int g = 0; g < 2; g++) {
        float4 va = *(const float4*)(pa + g*4);
        float fa[4] = {va.x, va.y, va.z, va.w};
        unsigned short ha[4], la[4];
#pragma unroll
        for (int j = 0; j < 4; j++) {
          unsigned short h = f2h(fa[j]); ha[j] = h; la[j] = f2h(fa[j] - h2f(h));
        }
        *(ushort4*)&sm[0*P + lo_ + g*4] = make_ushort4(ha[0], ha[1], ha[2], ha[3]);
        *(ushort4*)&sm[1*P + lo_ + g*4] = make_ushort4(la[0], la[1], la[2], la[3]);
      }
      size_t gb = (size_t)(v0 + srow)*C_ + k0 + sseg;
      *(float4*)&sm[2*P + lo_] = *(const float4*)&Bh_g[gb];
      *(float4*)&sm[3*P + lo_] = *(const float4*)&Bl_g[gb];
    }
    __syncthreads();
    f16x8 ah[2], al[2], bh[2], bl[2];
#pragma unroll
    for (int mt = 0; mt < 2; mt++) {
      int arow = (wv*32 + mt*16 + lx16)*LSTR + quad*8;
      ah[mt] = *(const f16x8*)&sm[0*P + arow];
      al[mt] = *(const f16x8*)&sm[1*P + arow];
    }
#pragma unroll
    for (int nt = 0; nt < 2; nt++) {
      int brow = (wu*32 + nt*16 + lx16)*LSTR + quad*8;
      bh[nt] = *(const f16x8*)&sm[2*P + brow];
      bl[nt] = *(const f16x8*)&sm[3*P + brow];
    }
#pragma unroll
    for (int mt = 0; mt < 2; mt++)
#pragma unroll
      for (int nt = 0; nt < 2; nt++) {
        f32x4 a = acc[mt][nt];
        a = __builtin_amdgcn_mfma_f32_16x16x32_f16(ah[mt], bh[nt], a, 0, 0, 0);
        a = __builtin_amdgcn_mfma_f32_16x16x32_f16(ah[mt], bl[nt], a, 0, 0, 0);
        a = __builtin_amdgcn_mfma_f32_16x16x32_f16(al[mt], bh[nt], a, 0, 0, 0);
        acc[mt][nt] = a;
      }
  }
  float scale = 1.0f / sqrtf(cnrm[m]);
  __syncthreads();
  unsigned short* Th = sm;             // [64][72]
  unsigned short* Tl = sm + 64*72;
#pragma unroll
  for (int mt = 0; mt < 2; mt++)
#pragma unroll
    for (int nt = 0; nt < 2; nt++)
#pragma unroll
      for (int i = 0; i < 4; i++) {
        int chl = wv*32 + mt*16 + quad*4 + i;
        int vl  = wu*32 + nt*16 + lx16;
        float ww = acc[mt][nt][i] * scale;
        unsigned short h = f2h(ww);
        unsigned short l = f2h(ww - h2f(h));
        Th[vl*72 + chl] = h;
        Tl[vl*72 + chl] = l;
      }
  __syncthreads();
  int vr = t >> 2, cs = (t & 3) * 16;
  size_t go = (size_t)(v0 + vr)*C_ + c0 + cs;
  *(float4*)&Oh[go]     = *(float4*)&Th[vr*72 + cs];
  *(float4*)&Oh[go + 8] = *(float4*)&Th[vr*72 + cs + 8];
  *(float4*)&Ol[go]     = *(float4*)&Tl[vr*72 + cs];
  *(float4*)&Ol[go + 8] = *(float4*)&Tl[vr*72 + cs + 8];
}

// ---------------- per-pixel channel sum-of-squares from whitened planes ----------------
__global__ __launch_bounds__(256) void k_ssq(const unsigned short* outT, float* ssq) {
  int b = blockIdx.y; int p = blockIdx.x * 256 + threadIdx.x;
  const unsigned short* h = outT + (size_t)(2*(2+b))*CN + (size_t)p*C_;
  const unsigned short* l = h + CN;
  float acc = 0.f;
  for (int c = 0; c < C_; c += 4) {
    ushort4 hv = *(const ushort4*)&h[c];
    ushort4 lv = *(const ushort4*)&l[c];
    float v0 = h2f(hv.x) + h2f(lv.x);
    float v1 = h2f(hv.y) + h2f(lv.y);
    float v2 = h2f(hv.z) + h2f(lv.z);
    float v3 = h2f(hv.w) + h2f(lv.w);
    acc += v0*v0 + v1*v1 + v2*v2 + v3*v3;
  }
  ssq[b*N_ + p] = acc;
}

// ---------------- patch reciprocal norms ----------------
__global__ __launch_bounds__(256) void k_rnorm(const float* ssq, float* rnorm) {
  int b = blockIdx.y; int s = blockIdx.x * 256 + threadIdx.x;
  int sy = s >> 6, sx = s & 63;
  float sum = 0.f;
#pragma unroll
  for (int ky = 0; ky < 3; ky++)
#pragma unroll
    for (int kx = 0; kx < 3; kx++)
      sum += ssq[b*N_ + refl(sy+ky-1)*64 + refl(sx+kx-1)];
  rnorm[b*N_ + s] = 1.f / (sqrtf(sum) + EPSF);
}

// ---------------- Gram via 2-way-split fp16 MFMA + fused x-blur (256x128 tile) ----------------
// 512 thr = 8 waves as 4x2: wave (wv,wu) owns 64x64 (4x4 16-tiles). Per k32 per wave:
// 8 hoisted A-frag reads + 8 streamed B-frag reads for 48 MFMAs (ratio 0.33, was 0.5).
// LDS: Ah,Al[256*40] + Bh,Bl[128*40] = 61440 B -> 2 blocks/CU; __launch_bounds__(512,4)
// caps VGPR at 128 (acc 64 + A-frags 32 + B 8 ~ 110). Grid (32,16) = 512 blocks.
// Epilogue: 4 bands of 64 rows (one vy each), per-band blur identical to old per-half code.
__global__ __launch_bounds__(512, 4) void k_gram(const unsigned short* Ah_g, const unsigned short* Al_g,
                                                 const unsigned short* Bh_g, const unsigned short* Bl_g,
                                                 float* Hx) {
  __shared__ unsigned short sm[(2*256 + 2*128)*LSTR];  // 61440 B; epilogue Gs[64][133] unioned
  const int PA = 256*LSTR;
  const int PB = 128*LSTR;
  int t = threadIdx.x;
  int v0 = blockIdx.y * 256, u0 = blockIdx.x * 128;
  int wave = t >> 6, lane = t & 63;
  int wv = wave >> 1, wu = wave & 1;       // wv 0..3 (64-row band), wu 0..1 (64-col band)
  int lx16 = lane & 15, quad = lane >> 4;
  f32x4 acc[4][4];
#pragma unroll
  for (int i = 0; i < 4; i++)
#pragma unroll
    for (int j = 0; j < 4; j++) acc[i][j] = (f32x4){0.f, 0.f, 0.f, 0.f};

  for (int k0 = 0; k0 < 256; k0 += 32) {
    __syncthreads();
    // stage A: 2 planes x 256 rows x 4 float4 = 2048 float4, 4/thread
#pragma unroll
    for (int i = 0; i < 4; i++) {
      int idx = t + i*512;
      int pl = idx >> 10;
      int r = (idx >> 2) & 255;
      int seg = (idx & 3) * 8;
      const unsigned short* src = pl ? Al_g : Ah_g;
      *(float4*)&sm[pl*PA + r*LSTR + seg] =
          *(const float4*)&src[(size_t)(v0 + r)*C_ + k0 + seg];
    }
    // stage B: 2 planes x 128 rows x 4 float4 = 1024 float4, 2/thread
#pragma unroll
    for (int i = 0; i < 2; i++) {
      int idx = t + i*512;
      int pl = idx >> 9;
      int r = (idx >> 2) & 127;
      int seg = (idx & 3) * 8;
      const unsigned short* src = pl ? Bl_g : Bh_g;
      *(float4*)&sm[2*PA + pl*PB + r*LSTR + seg] =
          *(const float4*)&src[(size_t)(u0 + r)*C_ + k0 + seg];
    }
    __syncthreads();
    int kb = quad*8;
    f16x8 ah[4], al[4];
#pragma unroll
    for (int mt = 0; mt < 4; mt++) {
      int arow = (wv*64 + mt*16 + lx16)*LSTR + kb;
      ah[mt] = *(const f16x8*)&sm[arow];
      al[mt] = *(const f16x8*)&sm[PA + arow];
    }
#pragma unroll
    for (int nt = 0; nt < 4; nt++) {
      int brow = (wu*64 + nt*16 + lx16)*LSTR + kb;
      f16x8 bh = *(const f16x8*)&sm[2*PA + brow];
      f16x8 bl = *(const f16x8*)&sm[2*PA + PB + brow];
#pragma unroll
      for (int mt = 0; mt < 4; mt++) {
        f32x4 a = acc[mt][nt];
        a = __builtin_amdgcn_mfma_f32_16x16x32_f16(ah[mt], bh, a, 0, 0, 0);
        a = __builtin_amdgcn_mfma_f32_16x16x32_f16(ah[mt], bl, a, 0, 0, 0);
        a = __builtin_amdgcn_mfma_f32_16x16x32_f16(al[mt], bh, a, 0, 0, 0);
        acc[mt][nt] = a;
      }
    }
  }
  // epilogue: 4 bands of 64 rows (one vy each); x-diagonal blur. Gs stride 133 fp32.
  float* Gs = (float*)sm;
  int btx = t & 15, bty = t >> 4;            // bty 0..31
#pragma unroll
  for (int h = 0; h < 4; h++) {
    __syncthreads();
    if (wv == h) {                           // 2 waves (wu=0,1) own this band's 64x128
#pragma unroll
      for (int mt = 0; mt < 4; mt++)
#pragma unroll
        for (int nt = 0; nt < 4; nt++)
#pragma unroll
          for (int i = 0; i < 4; i++)
            Gs[(mt*16 + quad*4 + i)*133 + wu*64 + nt*16 + lx16] = acc[mt][nt][i];
    }
    __syncthreads();
#pragma unroll
    for (int i = 0; i < 2; i++) {
      int px = bty + 32*i;                   // bank-spread remap
      int xm = refl(px-1), xp = refl(px+1);
#pragma unroll
      for (int jh = 0; jh < 2; jh++) {
        int ub = jh*64;
        float tmp[4];
#pragma unroll
        for (int j = 0; j < 4; j++) {
          int sx = btx*4 + j;
          int smm = refl(sx-1), sp = refl(sx+1);
          tmp[j] = Gs[xm*133 + ub + smm] + Gs[px*133 + ub + sx] + Gs[xp*133 + ub + sp];
        }
        *(float4*)&Hx[(size_t)(v0 + h*64 + px)*N_ + u0 + ub + btx*4] =
            make_float4(tmp[0], tmp[1], tmp[2], tmp[3]);
      }
    }
  }
}

// ---------------- y-diagonal blur of Hx + argmax (8-row grouping + shuffle reduction) -------
__global__ __launch_bounds__(256) void k_argmax(const float* Hx, const float* rnorm,
                                                int* idx, int b) {
  int blk = blockIdx.x, t = threadIdx.x;
  int q = blk >> 6, px = blk & 63;     // grid 512: q 0..7
  int py0 = 8*q;
  size_t R[10];
  R[0] = (size_t)(refl(py0-1)*64 + px) * N_;
#pragma unroll
  for (int j = 0; j < 8; j++) R[j+1] = (size_t)((py0+j)*64 + px) * N_;
  R[9] = (size_t)(refl(py0+8)*64 + px) * N_;
  float bv[8];
  int bs[8];
#pragma unroll
  for (int j = 0; j < 8; j++) { bv[j] = -1e30f; bs[j] = 0; }
  for (int s = t; s < N_; s += 256) {
    int sy = s >> 6, sx = s & 63;
    int u0 = refl(sy-1)*64 + sx, u2 = refl(sy+1)*64 + sx;
    float rn = rnorm[b*N_ + s];
#pragma unroll
    for (int j = 0; j < 8; j++) {
      float a = Hx[R[j] + u0] + Hx[R[j+1] + s] + Hx[R[j+2] + u2];
      float sc = a * rn;
      if (sc > bv[j]) { bv[j] = sc; bs[j] = s; }
    }
  }
  int lane = t & 63, wave = t >> 6;
#pragma unroll
  for (int off = 32; off > 0; off >>= 1) {
#pragma unroll
    for (int j = 0; j < 8; j++) {
      float ov = __shfl_down(bv[j], off);
      int   oi = __shfl_down(bs[j], off);
      if (ov > bv[j] || (ov == bv[j] && oi < bs[j])) { bv[j] = ov; bs[j] = oi; }
    }
  }
  __shared__ float swv[4][8];
  __shared__ int   swi[4][8];
  if (lane == 0)
#pragma unroll
    for (int j = 0; j < 8; j++) { swv[wave][j] = bv[j]; swi[wave][j] = bs[j]; }
  __syncthreads();
  if (t < 8) {
    float v = swv[0][t]; int ii = swi[0][t];
#pragma unroll
    for (int w = 1; w < 4; w++) {
      if (swv[w][t] > v || (swv[w][t] == v && swi[w][t] < ii)) { v = swv[w][t]; ii = swi[w][t]; }
    }
    idx[b*N_ + (py0 + t)*64 + px] = ii;
  }
}

// ---------------- deconv gather for batch b: 2 channels/thread via uint loads ----------------
__global__ __launch_bounds__(256) void k_recon(const unsigned short* nsTh,
                                               const unsigned short* nsTl,
                                               const int* idx_b, float* recont_b) {
  int t = threadIdx.x;
  int p = blockIdx.x * 2 + (t >> 7);
  int c0 = (t & 127) * 2;
  int py = p >> 6, px = p & 63;
  float a0 = 0.f, a1 = 0.f;
#pragma unroll
  for (int dy = 0; dy < 3; dy++)
#pragma unroll
    for (int dx = 0; dx < 3; dx++) {
      int q = refl(py+dy-1)*64 + refl(px+dx-1);
      int s = idx_b[q];
      int sy = s >> 6, sx = s & 63;
      size_t o = (size_t)(refl(sy+1-dy)*64 + refl(sx+1-dx))*C_ + c0;
      unsigned hv = *(const unsigned*)&nsTh[o];
      unsigned lv = *(const unsigned*)&nsTl[o];
      a0 += h2f((unsigned short)(hv & 0xffff)) + h2f((unsigned short)(lv & 0xffff));
      a1 += h2f((unsigned short)(hv >> 16))    + h2f((unsigned short)(lv >> 16));
    }
  float dc = ((py==0||py==63)?2.f:3.f) * ((px==0||px==63)?2.f:3.f);
  float rdc = 1.f / dc;
  *(float2*)&recont_b[(size_t)p*C_ + c0] = make_float2(a0 * rdc, a1 * rdc);
}

// ---------------- coloring (MFMA): out = Ym·recont^T ----------------
__global__ __launch_bounds__(256) void k_color(const float* Yall, const float* recont_all,
                                               const float* cnrm, const float* means,
                                               float* out_all) {
  __shared__ unsigned short sm[4*64*LSTR];
  int b = blockIdx.z;
  const float* Ym = Yall + (size_t)(2+b)*65536;
  const float* recont = recont_all + (size_t)b*CN;   // [4096][256]
  const float* smean = means + (2+b)*C_;
  float* out = out_all + (size_t)b*CN;               // [256][4096]
  int m0 = blockIdx.y * 64;
  int n0 = blockIdx.x * 64;
  f32x4 acc[2][2];
  mm64_3term(sm, Ym, recont, m0, n0, acc);
  float scale = sqrtf(cnrm[2+b]);
  int t = threadIdx.x, lane = t & 63;
  int wv = (t >> 7) & 1, wu = (t >> 6) & 1, lx16 = lane & 15, quad = lane >> 4;
#pragma unroll
  for (int mt = 0; mt < 2; mt++)
#pragma unroll
    for (int nt = 0; nt < 2; nt++)
#pragma unroll
      for (int i = 0; i < 4; i++) {
        int r = m0 + wv*32 + mt*16 + quad*4 + i;
        int c = n0 + wu*32 + nt*16 + lx16;
        out[(size_t)r*N_ + c] = acc[mt][nt][i]*scale + smean[r];
      }
}

extern "C" void kernel_launch(void* const* d_in, const int* in_sizes, int n_in,
                              void* d_out, int out_size, void* d_ws, size_t ws_size,
                              hipStream_t stream) {
  const float* content = (const float*)d_in[0];
  const float* style   = (const float*)d_in[1];
  float* out = (float*)d_out;

  // workspace layout (floats); total ~102 MiB
  float* F = (float*)d_ws;
  float* means  = F + 0;         // 4*256
  float* cnrm   = F + 1024;      // 4
  float* Y      = F + 264192;    // NS buffers
  float* Z      = F + 526336;
  float* Y2     = F + 788480;
  float* Z2     = F + 1050624;
  float* T      = F + 1312768;
  float* ncreg  = F + 1574912;   // outT (8 fp16 plane slots, 16 MB)
  float* nsreg  = F + 3672064;   // xcT  (8 fp16 plane slots, 16 MB)
  float* recont = F + 7866368;   // 2*CN fp32
  float* ssq    = F + 9963520;   // 2*4096
  float* rnorm  = F + 9971712;   // 2*4096
  int*   idx    = (int*)(F + 9979904); // 2*4096
  float* Hx     = F + 9988096;   // 4096*4096 (16.7M floats)

  // cov-phase aliases inside Hx (dead until k_gram at step 8)
  unsigned short* covsp = (unsigned short*)Hx;
  float* covp = Hx + 4194304;

  unsigned short* xcT  = (unsigned short*)nsreg;
  unsigned short* outT = (unsigned short*)ncreg;

  // 1-4. means, fused split, MFMA cov partials, trace, covred+nsinit
  k_mean<<<dim3(256,4), 256, 0, stream>>>(content, style, means);
  k_splitall<<<dim3(128,8,4), 256, 0, stream>>>(content, style, means, covsp, xcT);
  k_covmm<<<dim3(KSPLIT,4,4), 512, 0, stream>>>(covsp, covp);
  k_trace2<<<4, 256, 0, stream>>>(covp, means, cnrm);
  k_covred_init<<<dim3(256,4), 256, 0, stream>>>(covp, means, cnrm, Y, Z);
  // 5. NS iterations (separate launches — cooperative grid.sync measured 20x worse, r8)
  float *Ya = Y, *Za = Z, *Yb = Y2, *Zb = Z2;
  for (int it = 0; it < NS_ITERS; it++) {
    k_nsA<<<dim3(64,4), 256, 0, stream>>>(Za, Ya, T);
    k_nsB<<<dim3(64,4,2), 256, 0, stream>>>(Ya, Za, T, Yb, Zb);
    float* tmp;
    tmp = Ya; Ya = Yb; Yb = tmp;
    tmp = Za; Za = Zb; Zb = tmp;
  }
  // 6. whitening (MFMA) -> whitened transposed fp16 planes directly
  k_whitenT<<<dim3(64,4,4), 256, 0, stream>>>(xcT, Za, cnrm, outT);
  // 7. patch norms from planes
  k_ssq<<<dim3(16,2), 256, 0, stream>>>(outT, ssq);
  k_rnorm<<<dim3(16,2), 256, 0, stream>>>(ssq, rnorm);
  // 8. per batch: MFMA gram (256x128 tile) + x-blur -> 8-row y-blur+argmax -> recon
  for (int b = 0; b < 2; b++) {
    k_gram<<<dim3(32,16), 512, 0, stream>>>(outT + (size_t)(2*b)*CN,
                                            outT + (size_t)(2*b+1)*CN,
                                            outT + (size_t)(2*(2+b))*CN,
                                            outT + (size_t)(2*(2+b)+1)*CN, Hx);
    k_argmax<<<512, 256, 0, stream>>>(Hx, rnorm, idx, b);
    k_recon<<<2048, 256, 0, stream>>>(outT + (size_t)(2*(2+b))*CN,
                                      outT + (size_t)(2*(2+b)+1)*CN,
                                      idx + (size_t)b*N_, recont + (size_t)b*CN);
  }
  // 9. coloring (MFMA)
  k_color<<<dim3(64,4,2), 256, 0, stream>>>(Ya, recont, cnrm, means, out);
}